// Round 8
// baseline (183.284 us; speedup 1.0000x reference)
//
#include <hip/hip_runtime.h>

typedef _Float16 v8h __attribute__((ext_vector_type(8)));
typedef _Float16 v4h __attribute__((ext_vector_type(4)));
typedef _Float16 v2h __attribute__((ext_vector_type(2)));
typedef float v4f __attribute__((ext_vector_type(4)));

#define NB 64
#define CI 96
#define CE 576
#define CO 96
#define HW 784
#define SEC 144

#if defined(__has_builtin)
#if __has_builtin(__builtin_amdgcn_fdot2)
#define HAVE_FDOT2 1
#endif
#endif

__device__ __forceinline__ float fdot2(v2h a, v2h b, float c) {
#ifdef HAVE_FDOT2
  return __builtin_amdgcn_fdot2(a, b, c, false);
#else
  return (float)a[0] * (float)b[0] + ((float)a[1] * (float)b[1] + c);
#endif
}

__device__ __forceinline__ float clampf(float x, float lo, float hi) {
#if defined(__has_builtin)
#if __has_builtin(__builtin_amdgcn_fmed3f)
  return __builtin_amdgcn_fmed3f(x, lo, hi);   // v_med3_f32: 1 instr
#else
  return fminf(fmaxf(x, lo), hi);
#endif
#else
  return fminf(fmaxf(x, lo), hi);
#endif
}

// ---------------- K0: pack x into MFMA-B layout + convert GEMM weights -------
// One block per 16-hw tile (49 x 64 pack blocks + 49 cvt blocks).
__global__ __launch_bounds__(256) void k0_pack_cvt(const float* __restrict__ x,
                                                   _Float16* __restrict__ x_f,
                                                   const float* __restrict__ w_exp,
                                                   const float* __restrict__ w_proj,
                                                   _Float16* __restrict__ w_exp_h,
                                                   _Float16* __restrict__ w_proj_h) {
  __shared__ _Float16 xl[16][100];    // [hw_local][ci], pad 96->100
  const int tid = threadIdx.x;

  if (blockIdx.y == NB) {             // weight convert slice (49 blocks)
    for (int i = blockIdx.x * 256 + tid; i < CE * CI; i += 49 * 256) {
      w_exp_h[i]  = (_Float16)w_exp[i];
      w_proj_h[i] = (_Float16)w_proj[i];
    }
    return;
  }

  const int n = blockIdx.y;
  const int t = blockIdx.x;           // 16-hw tile index, hw0 = 16t
  const int hw0 = t * 16;

  // stage 1: 96 ci x 16 hw as 384 float4 loads (1.5 rounds)
  for (int idx = tid; idx < 384; idx += 256) {
    int ci = idx >> 2, seg = idx & 3;
    const float4 v = *(const float4*)&x[(n * CI + ci) * HW + hw0 + seg * 4];
    int r = seg * 4;
    xl[r + 0][ci] = (_Float16)(v.x - 128.0f);
    xl[r + 1][ci] = (_Float16)(v.y - 128.0f);
    xl[r + 2][ci] = (_Float16)(v.z - 128.0f);
    xl[r + 3][ci] = (_Float16)(v.w - 128.0f);
  }
  __syncthreads();

  // stage 2: 3 s-groups x 64 lanes -> v8h fragment stores (single round)
  if (tid < 192) {
    int s = tid >> 6, ln = tid & 63;
    int r = ln & 15, ci = s * 32 + (ln >> 4) * 8;
    v8h o;
#pragma unroll
    for (int j = 0; j < 8; ++j) o[j] = xl[r][ci + j];
    *(v8h*)&x_f[(((size_t)n * 49 + t) * 3 + s) * 512 + ln * 8] = o;
  }
}

// ---------------- K12: FUSED expand 1x1 (MFMA) + depthwise 5x5 ---------------
// block = (c-group of 16, image-half of 14 rows, n), 512 thr (8 waves).
// LDS ~35.8 KB -> 4 blocks/CU. Halo rows (+-2) recomputed by the expand MFMA.
// No XCD swizzle (round-4 measured: swizzle cut FETCH 86% but cost +2 us).
__global__ __launch_bounds__(512, 8) void k12_fused(const _Float16* __restrict__ x_f,
                                                    const _Float16* __restrict__ w_exp_h,
                                                    const float* __restrict__ b_exp,
                                                    const float* __restrict__ w_dw,
                                                    const float* __restrict__ b_dw,
                                                    _Float16* __restrict__ d_t,
                                                    float* __restrict__ d_sums2) {
  __shared__ _Float16 e_lds[16][18][38];   // 21888 B; width 38: all v2h in-row
  __shared__ _Float16 d_tile[16][392];     // 12544 B
  __shared__ _Float16 w_pairs[16][5][8];   // 1280 B
  const int tid = threadIdx.x;
  const int n = blockIdx.z;
  const int h = blockIdx.y;                // image half: rows 14h..14h+13
  const int c0 = blockIdx.x * 16;

  // zero conv image (covers halo + unwritten tail halves)
  {
    unsigned long long* z = (unsigned long long*)&e_lds[0][0][0];
    for (int idx = tid; idx < 16 * 18 * 38 * 2 / 8; idx += 512) z[idx] = 0ull;
  }
  // dw weight pairs [c][dy][w0,w1,w2,w3, w1,w2,w3,w4]
  for (int idx = tid; idx < 640; idx += 512) {
    int c = idx / 40, r = idx % 40, dy = r / 8, k = r % 8;
    int tap = (k < 4) ? k : (k - 3);
    w_pairs[c][dy][k] = (_Float16)w_dw[(c0 + c) * 25 + dy * 5 + tap];
  }
  __syncthreads();

  const int wv = tid >> 6, lane = tid & 63;
  const int l15 = lane & 15, q = lane >> 4;

  // ---- phase 1: expand GEMM over 16 input rows (t-tiles 21h .. 21h+27) ----
  {
    const _Float16* wrow = &w_exp_h[(c0 + l15) * CI + q * 8];
    v8h a0 = *(const v8h*)(wrow);
    v8h a1 = *(const v8h*)(wrow + 32);
    v8h a2 = *(const v8h*)(wrow + 64);
    float bia3[4], bia2[4];                // bias pre-folded into fma constants
#pragma unroll
    for (int r = 0; r < 4; ++r) {
      float b = b_exp[c0 + q * 4 + r];
      bia3[r] = fmaf(b, 5.0e-4f, 3.0f);                 // deq + 3 path
      bia2[r] = b * (5.0e-4f * 25.0f / 6.0f);           // deq*25/6 path
    }

    const int ir0 = 14 * h - 2;                 // input row at LDS row 0
    const _Float16* xb = x_f + (size_t)n * (49 * 3 * 512) + lane * 8;
    // incremental y/xx tracking: per-iter hw += 128 = 4*28 + 16
    int hw0 = (21 * h + wv) * 16 + l15;
    int y = hw0 / 28;
    int xx = hw0 - y * 28;
#pragma unroll
    for (int it = 0; it < 4; ++it) {
      int t_l = wv + it * 8;
      if (t_l < 28) {                           // wave-uniform guard
        int t = 21 * h + t_l;
        const _Float16* xt = xb + (size_t)t * (3 * 512);
        v8h b0 = *(const v8h*)(xt);
        v8h b1 = *(const v8h*)(xt + 512);
        v8h b2 = *(const v8h*)(xt + 1024);
        v4f acc = (v4f){0.f, 0.f, 0.f, 0.f};
        acc = __builtin_amdgcn_mfma_f32_16x16x32_f16(a0, b0, acc, 0, 0, 0);
        acc = __builtin_amdgcn_mfma_f32_16x16x32_f16(a1, b1, acc, 0, 0, 0);
        acc = __builtin_amdgcn_mfma_f32_16x16x32_f16(a2, b2, acc, 0, 0, 0);
        _Float16* dst = &e_lds[q * 4][y - ir0][6 + xx];
#pragma unroll
        for (int r = 0; r < 4; ++r) {
          // hardswish+requant: fma, med3, fma, mul, med3, cvt
          float t1  = fmaf(acc[r], 5.0e-4f, bia3[r]);               // deq+3
          float cl  = clampf(t1, 0.0f, 6.0f);
          float a2v = fmaf(acc[r], 5.0e-4f * 25.0f / 6.0f, bia2[r]); // deq*25/6
          float ev  = clampf(a2v * cl, -128.0f, 127.0f);            // e-128
          dst[r * (18 * 38)] = (_Float16)ev;                        // imm-offset stores
        }
      }
      xx += 16; y += 4;
      if (xx >= 28) { xx -= 28; ++y; }
    }
  }
  __syncthreads();

  // ---- phase 2: depthwise 5x5; lane = (row ry = l>>1, x-half xh = l&1) ----
  const int c = tid >> 5, l = tid & 31;
  v2h W01[5], W23[5], W12[5], W34[5];
  float W0s[5], W4s[5];
#pragma unroll
  for (int dy = 0; dy < 5; ++dy) {
    W01[dy] = *(const v2h*)&w_pairs[c][dy][0];
    W23[dy] = *(const v2h*)&w_pairs[c][dy][2];
    W12[dy] = *(const v2h*)&w_pairs[c][dy][4];
    W34[dy] = *(const v2h*)&w_pairs[c][dy][6];
    W0s[dy] = (float)W01[dy][0];
    W4s[dy] = (float)W34[dy][1];
  }
  const float bc = b_dw[c0 + c];

#define DW_REQUANT(oo, dvv)                                                   \
  {                                                                           \
    float t1_ = fmaf((oo), 4.0e-4f, 3.0f);                                    \
    float cl_ = clampf(t1_, 0.0f, 6.0f);                                      \
    dvv = clampf((oo) * (4.0e-4f * 25.0f / 6.0f) * cl_, -128.0f, 127.0f);     \
  }

  float csum = 0.0f;
  if (l < 28) {
    const int ry = l >> 1;       // local output row 0..13
    const int bx = (l & 1) * 14; // x-half base
    v2h P0[5], P1[5], P2[5], P3[5];
#pragma unroll
    for (int dy = 0; dy < 5; ++dy) {
      const _Float16* row = &e_lds[c][ry + dy][bx];
      P0[dy] = *(const v2h*)(row + 4);    // pixels bx-2,bx-1
      P1[dy] = *(const v2h*)(row + 6);
      P2[dy] = *(const v2h*)(row + 8);
      P3[dy] = *(const v2h*)(row + 10);
    }
#pragma unroll
    for (int xi = 0; xi < 3; ++xi) {      // x0 = bx, bx+4, bx+8
      const int x0 = bx + xi * 4;
      float o0 = bc, o1 = bc, o2 = bc, o3 = bc;
#pragma unroll
      for (int dy = 0; dy < 5; ++dy) {
        o0 = fdot2(P0[dy], W01[dy], o0);
        o0 = fdot2(P1[dy], W23[dy], o0);
        o0 += (float)P2[dy][0] * W4s[dy];
        o1 += (float)P0[dy][1] * W0s[dy];
        o1 = fdot2(P1[dy], W12[dy], o1);
        o1 = fdot2(P2[dy], W34[dy], o1);
        o2 = fdot2(P1[dy], W01[dy], o2);
        o2 = fdot2(P2[dy], W23[dy], o2);
        o2 += (float)P3[dy][0] * W4s[dy];
        o3 += (float)P1[dy][1] * W0s[dy];
        o3 = fdot2(P2[dy], W12[dy], o3);
        o3 = fdot2(P3[dy], W34[dy], o3);
      }
      float d0, d1, d2, d3;
      DW_REQUANT(o0, d0); DW_REQUANT(o1, d1);
      DW_REQUANT(o2, d2); DW_REQUANT(o3, d3);
      csum += (d0 + d1) + (d2 + d3);
      v2h dva, dvb;
      dva[0] = (_Float16)d0; dva[1] = (_Float16)d1;
      dvb[0] = (_Float16)d2; dvb[1] = (_Float16)d3;
      *(v2h*)&d_tile[c][ry * 28 + x0]     = dva;   // b32 stores, 4B-aligned
      *(v2h*)&d_tile[c][ry * 28 + x0 + 2] = dvb;
      // slide window (last slide reads halves up to 37 -> zeroed tail, in-row)
#pragma unroll
      for (int dy = 0; dy < 5; ++dy) {
        const _Float16* row = &e_lds[c][ry + dy][bx];
        P0[dy] = P2[dy];
        P1[dy] = P3[dy];
        P2[dy] = *(const v2h*)(row + x0 - bx + 12);
        P3[dy] = *(const v2h*)(row + x0 - bx + 14);
      }
    }
    {  // tail: x0 = bx+12, outputs o0,o1 only
      float o0 = bc, o1 = bc;
#pragma unroll
      for (int dy = 0; dy < 5; ++dy) {
        o0 = fdot2(P0[dy], W01[dy], o0);
        o0 = fdot2(P1[dy], W23[dy], o0);
        o0 += (float)P2[dy][0] * W4s[dy];
        o1 += (float)P0[dy][1] * W0s[dy];
        o1 = fdot2(P1[dy], W12[dy], o1);
        o1 = fdot2(P2[dy], W34[dy], o1);
      }
      float d0, d1;
      DW_REQUANT(o0, d0); DW_REQUANT(o1, d1);
      csum += d0 + d1;
      v2h dv; dv[0] = (_Float16)d0; dv[1] = (_Float16)d1;
      *(v2h*)&d_tile[c][ry * 28 + bx + 12] = dv;
    }
  }
#pragma unroll
  for (int m = 16; m >= 1; m >>= 1) csum += __shfl_xor(csum, m);
  if (l == 0) d_sums2[((size_t)h * NB + n) * CE + c0 + c] = csum;

  __syncthreads();
  // ---- phase 3: k-packed writeout d_t[n][cg][hw][8], hw in [392h, 392h+392) ----
  const size_t obase = ((size_t)n * 72 + (c0 >> 3)) * 784 + 392 * h;
  if (tid < 392) {
    int hw_l = tid;
    v8h o0, o1;
#pragma unroll
    for (int j = 0; j < 8; ++j) { o0[j] = d_tile[j][hw_l]; o1[j] = d_tile[8 + j][hw_l]; }
    *(v8h*)&d_t[(obase + hw_l) * 8] = o0;
    *(v8h*)&d_t[(obase + 784 + hw_l) * 8] = o1;
  }
}

// ---------------- K3: fused SE (fc1 redundant + fc2 slice) -------------------
// 512 blocks = 8 per image. Each block redundantly computes the full 144-value
// fc1 into LDS (arithmetic verbatim from the passing k3a; w_se1 reads go
// L2-hot after first touch), then its 72-output slice of fc2 (verbatim from
// k3b, g1 read from LDS instead of global). Removes one dispatch + the g1
// global round-trip while keeping 512-way block parallelism (round-1's
// one-block-per-n version was latency-bound at 73 us; this is not that).
__global__ __launch_bounds__(256) void k3_se_fused(const float* __restrict__ d_sums2,
                                                   const float* __restrict__ w_se1,
                                                   const float* __restrict__ b_se1,
                                                   const float* __restrict__ w_se2,
                                                   const float* __restrict__ b_se2,
                                                   _Float16* __restrict__ g2h) {
  __shared__ float g1s[SEC];
  const int tid = threadIdx.x;
  const int wv = tid >> 6, lane = tid & 63;
  const int n = blockIdx.x >> 3;       // 8 blocks per n
  const int part = blockIdx.x & 7;     // fc2 outputs part*72 .. part*72+71

  // ---- fc1: 4 waves x 36 outputs (identical math to k3a) ----
  const float* s0 = &d_sums2[(size_t)n * CE];
  const float* s1 = &d_sums2[((size_t)NB + n) * CE];
  float sreg[9];
#pragma unroll
  for (int s = 0; s < 9; ++s) {
    int cc = lane + s * 64;
    sreg[s] = s0[cc] + s1[cc];
  }
  for (int i = 0; i < 36; i += 2) {
    const int oa = wv * 36 + i, ob = oa + 1;
    const float* wa = &w_se1[(size_t)oa * CE];
    const float* wb = &w_se1[(size_t)ob * CE];
    float pa = 0.f, pb = 0.f;
#pragma unroll
    for (int s = 0; s < 9; ++s) {
      pa = fmaf(wa[lane + 64 * s], sreg[s], pa);
      pb = fmaf(wb[lane + 64 * s], sreg[s], pb);
    }
#pragma unroll
    for (int m = 32; m >= 1; m >>= 1) {
      pa += __shfl_xor(pa, m);
      pb += __shfl_xor(pb, m);
    }
    if (lane == 0) {
      // g1 = clamp((p/784 + b)*(1/75) + 128, 0, 255) - 128
      g1s[oa] = clampf(fmaf(pa, 1.0f / 58800.0f,
                            fmaf(b_se1[oa], 1.0f / 75.0f, 128.0f)),
                       0.0f, 255.0f) - 128.0f;
      g1s[ob] = clampf(fmaf(pb, 1.0f / 58800.0f,
                            fmaf(b_se1[ob], 1.0f / 75.0f, 128.0f)),
                       0.0f, 255.0f) - 128.0f;
    }
  }
  __syncthreads();

  // ---- fc2: 4 waves x 18 outputs of this block's 72-slice (k3b math) ----
  const float gl0  = g1s[lane];
  const float gl64 = g1s[lane + 64];
  const float gl128 = (lane < 16) ? g1s[lane + 128] : 0.0f;
  for (int i = 0; i < 18; ++i) {
    const int o = part * 72 + wv * 18 + i;
    const float* wrow = &w_se2[(size_t)o * SEC];
    float w2 = (lane < 16) ? wrow[lane + 128] : 0.0f;
    float p = fmaf(wrow[lane], gl0, fmaf(wrow[lane + 64], gl64, w2 * gl128));
#pragma unroll
    for (int m = 32; m >= 1; m >>= 1) p += __shfl_xor(p, m);
    if (lane == 0) {
      float t = fmaf(p, 3.0e-4f, fmaf(b_se2[o], 3.0e-4f, 3.0f));
      g2h[(size_t)n * CE + o] = (_Float16)(clampf(t, 0.0f, 6.0f) * (1.0f / 6.0f));
    }
  }
}

// ---------------- K4: gated project 1x1 + residual add -> out fp32 -----------
// acc[7] form (reuse beats occupancy: round-6 acc[1] variant was 62.6 us).
// Ping-pong prefetch + XCD swizzle (all of an n's 14 blocks on one XCD so the
// 2nd co-group's d_t read L2-hits; measured ~-6 us in round 4).
__global__ __launch_bounds__(192) void k4_proj(const _Float16* __restrict__ d_t,
                                               const _Float16* __restrict__ g2h,
                                               const _Float16* __restrict__ w_proj_h,
                                               const float* __restrict__ b_proj,
                                               const float* __restrict__ x,
                                               float* __restrict__ out) {
  const int tid = threadIdx.x;

  // XCD-aware remap: 896 blocks = 8 XCD x 112 slots; 14 blocks (7hw x 2co)/n
  const int flat = blockIdx.x + 7 * blockIdx.y + 14 * blockIdx.z;
  const int xcd = flat & 7, slot = flat >> 3;
  const int nl = slot / 14, w14 = slot - nl * 14;
  const int n = xcd * 8 + nl;
  const int byy = w14 / 7;
  const int co0 = byy * 48;
  const int hw0 = (w14 - byy * 7) * 112;

  const int wv = tid >> 6, lane = tid & 63;
  const int l15 = lane & 15, q = lane >> 4;

  v4f acc[7];
#pragma unroll
  for (int t = 0; t < 7; ++t) acc[t] = (v4f){0.f, 0.f, 0.f, 0.f};

  const _Float16* dbase = d_t + (((size_t)n * 72 + q) * 784 + hw0 + l15) * 8;
  const _Float16* abase = &w_proj_h[(co0 + wv * 16 + l15) * CE + q * 8];
  const _Float16* gbase = &g2h[(size_t)n * CE + q * 8];

#define K4_LOAD(SUF, KS)                                                      \
  {                                                                           \
    const int ks_ = (KS);                                                     \
    a##SUF = *(const v8h*)(abase + ks_ * 32);                                 \
    g##SUF = *(const v8h*)(gbase + ks_ * 32);                                 \
    const _Float16* dk_ = dbase + (size_t)ks_ * (4 * 784 * 8);                \
    _Pragma("unroll")                                                         \
    for (int t = 0; t < 7; ++t) b##SUF[t] = *(const v8h*)(dk_ + t * (16 * 8));\
  }
#define K4_COMPUTE(SUF)                                                       \
  {                                                                           \
    v8h ag_ = a##SUF * g##SUF;                                                \
    _Pragma("unroll")                                                         \
    for (int t = 0; t < 7; ++t)                                               \
      acc[t] = __builtin_amdgcn_mfma_f32_16x16x32_f16(ag_, b##SUF[t],         \
                                                      acc[t], 0, 0, 0);       \
  }

  v8h aA, gA, bA[7], aB, gB, bB[7];
  K4_LOAD(A, 0);
#pragma unroll
  for (int ks = 0; ks < 18; ks += 2) {
    K4_LOAD(B, ks + 1);          // prefetch odd while computing even
    K4_COMPUTE(A);
    if (ks + 2 < 18) K4_LOAD(A, ks + 2);  // prefetch next even
    K4_COMPUTE(B);
  }

  float biaf[4];   // bias pre-folded: p = med3(fma(acc, 8e-3, biaf), 0, 255)
#pragma unroll
  for (int r = 0; r < 4; ++r)
    biaf[r] = fmaf(b_proj[co0 + wv * 16 + q * 4 + r], 8.0e-3f, 128.0f);

#pragma unroll
  for (int t = 0; t < 7; ++t) {
#pragma unroll
    for (int r = 0; r < 4; ++r) {
      int co = co0 + wv * 16 + q * 4 + r;
      int hw = hw0 + t * 16 + l15;
      float p  = clampf(fmaf(acc[t][r], 8.0e-3f, biaf[r]), 0.0f, 255.0f);
      float xv = x[(n * CO + co) * HW + hw];
      // (xv-128)*g + (p-128)*g + 128 = g*(xv+p) - 85.333..., g = 5/6
      float o = fmaf(xv + p, 0.8333333333f, -85.33333333f);
      out[(n * CO + co) * HW + hw] = clampf(o, 0.0f, 255.0f);
    }
  }
}

extern "C" void kernel_launch(void* const* d_in, const int* in_sizes, int n_in,
                              void* d_out, int out_size, void* d_ws, size_t ws_size,
                              hipStream_t stream) {
  const float* x      = (const float*)d_in[0];
  const float* w_exp  = (const float*)d_in[1];
  const float* b_exp  = (const float*)d_in[2];
  const float* w_dw   = (const float*)d_in[3];
  const float* b_dw   = (const float*)d_in[4];
  const float* w_se1  = (const float*)d_in[5];
  const float* b_se1  = (const float*)d_in[6];
  const float* w_se2  = (const float*)d_in[7];
  const float* b_se2  = (const float*)d_in[8];
  const float* w_proj = (const float*)d_in[9];
  const float* b_proj = (const float*)d_in[10];
  float* out = (float*)d_out;

  char* ws = (char*)d_ws;
  const size_t SZ_W  = (size_t)CE * CI * 2;            // 110592 B
  const size_t SZ_XF = (size_t)NB * 49 * 3 * 512 * 2;  // 9633792 B
  const size_t SZ_D  = (size_t)NB * CE * HW * 2;       // 57802752 B
  const size_t SZ_S2 = (size_t)2 * NB * CE * 4;        // 294912 B
  _Float16* w_exp_h  = (_Float16*)(ws);
  _Float16* w_proj_h = (_Float16*)(ws + SZ_W);
  _Float16* x_f      = (_Float16*)(ws + 2 * SZ_W);
  _Float16* d_t      = (_Float16*)(ws + 2 * SZ_W + SZ_XF);    // [n][72][784][8]
  float*    d_sums2  = (float*)   (ws + 2 * SZ_W + SZ_XF + SZ_D);
  _Float16* g2h      = (_Float16*)(ws + 2 * SZ_W + SZ_XF + SZ_D + SZ_S2);
  // total ws use: ~68 MB

  k0_pack_cvt<<<dim3(49, NB + 1), 256, 0, stream>>>(x, x_f, w_exp, w_proj, w_exp_h, w_proj_h);
  k12_fused<<<dim3(36, 2, NB), 512, 0, stream>>>(x_f, w_exp_h, b_exp, w_dw, b_dw, d_t, d_sums2);
  k3_se_fused<<<dim3(512), 256, 0, stream>>>(d_sums2, w_se1, b_se1, w_se2, b_se2, g2h);
  k4_proj<<<dim3(7, 2, NB), 192, 0, stream>>>(d_t, g2h, w_proj_h, b_proj, x, out);
}

// Round 9
// 170.613 us; speedup vs baseline: 1.0743x; 1.0743x over previous
//
#include <hip/hip_runtime.h>

typedef _Float16 v8h __attribute__((ext_vector_type(8)));
typedef _Float16 v4h __attribute__((ext_vector_type(4)));
typedef _Float16 v2h __attribute__((ext_vector_type(2)));
typedef float v4f __attribute__((ext_vector_type(4)));

#define NB 64
#define CI 96
#define CE 576
#define CO 96
#define HW 784
#define SEC 144

#if defined(__has_builtin)
#if __has_builtin(__builtin_amdgcn_fdot2)
#define HAVE_FDOT2 1
#endif
#endif

__device__ __forceinline__ float fdot2(v2h a, v2h b, float c) {
#ifdef HAVE_FDOT2
  return __builtin_amdgcn_fdot2(a, b, c, false);
#else
  return (float)a[0] * (float)b[0] + ((float)a[1] * (float)b[1] + c);
#endif
}

__device__ __forceinline__ float clampf(float x, float lo, float hi) {
#if defined(__has_builtin)
#if __has_builtin(__builtin_amdgcn_fmed3f)
  return __builtin_amdgcn_fmed3f(x, lo, hi);   // v_med3_f32: 1 instr
#else
  return fminf(fmaxf(x, lo), hi);
#endif
#else
  return fminf(fmaxf(x, lo), hi);
#endif
}

// ---------------- K0: pack x into MFMA-B layout + convert GEMM weights -------
// One block per 16-hw tile (49 x 64 pack blocks + 49 cvt blocks).
__global__ __launch_bounds__(256) void k0_pack_cvt(const float* __restrict__ x,
                                                   _Float16* __restrict__ x_f,
                                                   const float* __restrict__ w_exp,
                                                   const float* __restrict__ w_proj,
                                                   _Float16* __restrict__ w_exp_h,
                                                   _Float16* __restrict__ w_proj_h) {
  __shared__ _Float16 xl[16][100];    // [hw_local][ci], pad 96->100
  const int tid = threadIdx.x;

  if (blockIdx.y == NB) {             // weight convert slice (49 blocks)
    for (int i = blockIdx.x * 256 + tid; i < CE * CI; i += 49 * 256) {
      w_exp_h[i]  = (_Float16)w_exp[i];
      w_proj_h[i] = (_Float16)w_proj[i];
    }
    return;
  }

  const int n = blockIdx.y;
  const int t = blockIdx.x;           // 16-hw tile index, hw0 = 16t
  const int hw0 = t * 16;

  // stage 1: 96 ci x 16 hw as 384 float4 loads (1.5 rounds)
  for (int idx = tid; idx < 384; idx += 256) {
    int ci = idx >> 2, seg = idx & 3;
    const float4 v = *(const float4*)&x[(n * CI + ci) * HW + hw0 + seg * 4];
    int r = seg * 4;
    xl[r + 0][ci] = (_Float16)(v.x - 128.0f);
    xl[r + 1][ci] = (_Float16)(v.y - 128.0f);
    xl[r + 2][ci] = (_Float16)(v.z - 128.0f);
    xl[r + 3][ci] = (_Float16)(v.w - 128.0f);
  }
  __syncthreads();

  // stage 2: 3 s-groups x 64 lanes -> v8h fragment stores (single round)
  if (tid < 192) {
    int s = tid >> 6, ln = tid & 63;
    int r = ln & 15, ci = s * 32 + (ln >> 4) * 8;
    v8h o;
#pragma unroll
    for (int j = 0; j < 8; ++j) o[j] = xl[r][ci + j];
    *(v8h*)&x_f[(((size_t)n * 49 + t) * 3 + s) * 512 + ln * 8] = o;
  }
}

// ---------------- K12: FUSED expand 1x1 (MFMA) + depthwise 5x5 ---------------
// block = (c-group of 16, image-half of 14 rows, n), 512 thr (8 waves).
// LDS ~35.8 KB -> 4 blocks/CU. Halo rows (+-2) recomputed by the expand MFMA.
// No XCD swizzle (round-4 measured: swizzle cut FETCH 86% but cost +2 us).
__global__ __launch_bounds__(512, 8) void k12_fused(const _Float16* __restrict__ x_f,
                                                    const _Float16* __restrict__ w_exp_h,
                                                    const float* __restrict__ b_exp,
                                                    const float* __restrict__ w_dw,
                                                    const float* __restrict__ b_dw,
                                                    _Float16* __restrict__ d_t,
                                                    float* __restrict__ d_sums2) {
  __shared__ _Float16 e_lds[16][18][38];   // 21888 B; width 38: all v2h in-row
  __shared__ _Float16 d_tile[16][392];     // 12544 B
  __shared__ _Float16 w_pairs[16][5][8];   // 1280 B
  const int tid = threadIdx.x;
  const int n = blockIdx.z;
  const int h = blockIdx.y;                // image half: rows 14h..14h+13
  const int c0 = blockIdx.x * 16;

  // zero conv image (covers halo + unwritten tail halves)
  {
    unsigned long long* z = (unsigned long long*)&e_lds[0][0][0];
    for (int idx = tid; idx < 16 * 18 * 38 * 2 / 8; idx += 512) z[idx] = 0ull;
  }
  // dw weight pairs [c][dy][w0,w1,w2,w3, w1,w2,w3,w4]
  for (int idx = tid; idx < 640; idx += 512) {
    int c = idx / 40, r = idx % 40, dy = r / 8, k = r % 8;
    int tap = (k < 4) ? k : (k - 3);
    w_pairs[c][dy][k] = (_Float16)w_dw[(c0 + c) * 25 + dy * 5 + tap];
  }
  __syncthreads();

  const int wv = tid >> 6, lane = tid & 63;
  const int l15 = lane & 15, q = lane >> 4;

  // ---- phase 1: expand GEMM over 16 input rows (t-tiles 21h .. 21h+27) ----
  {
    const _Float16* wrow = &w_exp_h[(c0 + l15) * CI + q * 8];
    v8h a0 = *(const v8h*)(wrow);
    v8h a1 = *(const v8h*)(wrow + 32);
    v8h a2 = *(const v8h*)(wrow + 64);
    float bia3[4], bia2[4];                // bias pre-folded into fma constants
#pragma unroll
    for (int r = 0; r < 4; ++r) {
      float b = b_exp[c0 + q * 4 + r];
      bia3[r] = fmaf(b, 5.0e-4f, 3.0f);                 // deq + 3 path
      bia2[r] = b * (5.0e-4f * 25.0f / 6.0f);           // deq*25/6 path
    }

    const int ir0 = 14 * h - 2;                 // input row at LDS row 0
    const _Float16* xb = x_f + (size_t)n * (49 * 3 * 512) + lane * 8;
    // incremental y/xx tracking: per-iter hw += 128 = 4*28 + 16
    int hw0 = (21 * h + wv) * 16 + l15;
    int y = hw0 / 28;
    int xx = hw0 - y * 28;
#pragma unroll
    for (int it = 0; it < 4; ++it) {
      int t_l = wv + it * 8;
      if (t_l < 28) {                           // wave-uniform guard
        int t = 21 * h + t_l;
        const _Float16* xt = xb + (size_t)t * (3 * 512);
        v8h b0 = *(const v8h*)(xt);
        v8h b1 = *(const v8h*)(xt + 512);
        v8h b2 = *(const v8h*)(xt + 1024);
        v4f acc = (v4f){0.f, 0.f, 0.f, 0.f};
        acc = __builtin_amdgcn_mfma_f32_16x16x32_f16(a0, b0, acc, 0, 0, 0);
        acc = __builtin_amdgcn_mfma_f32_16x16x32_f16(a1, b1, acc, 0, 0, 0);
        acc = __builtin_amdgcn_mfma_f32_16x16x32_f16(a2, b2, acc, 0, 0, 0);
        _Float16* dst = &e_lds[q * 4][y - ir0][6 + xx];
#pragma unroll
        for (int r = 0; r < 4; ++r) {
          // hardswish+requant: fma, med3, fma, mul, med3, cvt
          float t1  = fmaf(acc[r], 5.0e-4f, bia3[r]);               // deq+3
          float cl  = clampf(t1, 0.0f, 6.0f);
          float a2v = fmaf(acc[r], 5.0e-4f * 25.0f / 6.0f, bia2[r]); // deq*25/6
          float ev  = clampf(a2v * cl, -128.0f, 127.0f);            // e-128
          dst[r * (18 * 38)] = (_Float16)ev;                        // imm-offset stores
        }
      }
      xx += 16; y += 4;
      if (xx >= 28) { xx -= 28; ++y; }
    }
  }
  __syncthreads();

  // ---- phase 2: depthwise 5x5; lane = (row ry = l>>1, x-half xh = l&1) ----
  const int c = tid >> 5, l = tid & 31;
  v2h W01[5], W23[5], W12[5], W34[5];
  float W0s[5], W4s[5];
#pragma unroll
  for (int dy = 0; dy < 5; ++dy) {
    W01[dy] = *(const v2h*)&w_pairs[c][dy][0];
    W23[dy] = *(const v2h*)&w_pairs[c][dy][2];
    W12[dy] = *(const v2h*)&w_pairs[c][dy][4];
    W34[dy] = *(const v2h*)&w_pairs[c][dy][6];
    W0s[dy] = (float)W01[dy][0];
    W4s[dy] = (float)W34[dy][1];
  }
  const float bc = b_dw[c0 + c];

#define DW_REQUANT(oo, dvv)                                                   \
  {                                                                           \
    float t1_ = fmaf((oo), 4.0e-4f, 3.0f);                                    \
    float cl_ = clampf(t1_, 0.0f, 6.0f);                                      \
    dvv = clampf((oo) * (4.0e-4f * 25.0f / 6.0f) * cl_, -128.0f, 127.0f);     \
  }

  float csum = 0.0f;
  if (l < 28) {
    const int ry = l >> 1;       // local output row 0..13
    const int bx = (l & 1) * 14; // x-half base
    v2h P0[5], P1[5], P2[5], P3[5];
#pragma unroll
    for (int dy = 0; dy < 5; ++dy) {
      const _Float16* row = &e_lds[c][ry + dy][bx];
      P0[dy] = *(const v2h*)(row + 4);    // pixels bx-2,bx-1
      P1[dy] = *(const v2h*)(row + 6);
      P2[dy] = *(const v2h*)(row + 8);
      P3[dy] = *(const v2h*)(row + 10);
    }
#pragma unroll
    for (int xi = 0; xi < 3; ++xi) {      // x0 = bx, bx+4, bx+8
      const int x0 = bx + xi * 4;
      float o0 = bc, o1 = bc, o2 = bc, o3 = bc;
#pragma unroll
      for (int dy = 0; dy < 5; ++dy) {
        o0 = fdot2(P0[dy], W01[dy], o0);
        o0 = fdot2(P1[dy], W23[dy], o0);
        o0 += (float)P2[dy][0] * W4s[dy];
        o1 += (float)P0[dy][1] * W0s[dy];
        o1 = fdot2(P1[dy], W12[dy], o1);
        o1 = fdot2(P2[dy], W34[dy], o1);
        o2 = fdot2(P1[dy], W01[dy], o2);
        o2 = fdot2(P2[dy], W23[dy], o2);
        o2 += (float)P3[dy][0] * W4s[dy];
        o3 += (float)P1[dy][1] * W0s[dy];
        o3 = fdot2(P2[dy], W12[dy], o3);
        o3 = fdot2(P3[dy], W34[dy], o3);
      }
      float d0, d1, d2, d3;
      DW_REQUANT(o0, d0); DW_REQUANT(o1, d1);
      DW_REQUANT(o2, d2); DW_REQUANT(o3, d3);
      csum += (d0 + d1) + (d2 + d3);
      v2h dva, dvb;
      dva[0] = (_Float16)d0; dva[1] = (_Float16)d1;
      dvb[0] = (_Float16)d2; dvb[1] = (_Float16)d3;
      *(v2h*)&d_tile[c][ry * 28 + x0]     = dva;   // b32 stores, 4B-aligned
      *(v2h*)&d_tile[c][ry * 28 + x0 + 2] = dvb;
      // slide window (last slide reads halves up to 37 -> zeroed tail, in-row)
#pragma unroll
      for (int dy = 0; dy < 5; ++dy) {
        const _Float16* row = &e_lds[c][ry + dy][bx];
        P0[dy] = P2[dy];
        P1[dy] = P3[dy];
        P2[dy] = *(const v2h*)(row + x0 - bx + 12);
        P3[dy] = *(const v2h*)(row + x0 - bx + 14);
      }
    }
    {  // tail: x0 = bx+12, outputs o0,o1 only
      float o0 = bc, o1 = bc;
#pragma unroll
      for (int dy = 0; dy < 5; ++dy) {
        o0 = fdot2(P0[dy], W01[dy], o0);
        o0 = fdot2(P1[dy], W23[dy], o0);
        o0 += (float)P2[dy][0] * W4s[dy];
        o1 += (float)P0[dy][1] * W0s[dy];
        o1 = fdot2(P1[dy], W12[dy], o1);
        o1 = fdot2(P2[dy], W34[dy], o1);
      }
      float d0, d1;
      DW_REQUANT(o0, d0); DW_REQUANT(o1, d1);
      csum += d0 + d1;
      v2h dv; dv[0] = (_Float16)d0; dv[1] = (_Float16)d1;
      *(v2h*)&d_tile[c][ry * 28 + bx + 12] = dv;
    }
  }
#pragma unroll
  for (int m = 16; m >= 1; m >>= 1) csum += __shfl_xor(csum, m);
  if (l == 0) d_sums2[((size_t)h * NB + n) * CE + c0 + c] = csum;

  __syncthreads();
  // ---- phase 3: k-packed writeout d_t[n][cg][hw][8], hw in [392h, 392h+392) ----
  const size_t obase = ((size_t)n * 72 + (c0 >> 3)) * 784 + 392 * h;
  if (tid < 392) {
    int hw_l = tid;
    v8h o0, o1;
#pragma unroll
    for (int j = 0; j < 8; ++j) { o0[j] = d_tile[j][hw_l]; o1[j] = d_tile[8 + j][hw_l]; }
    *(v8h*)&d_t[(obase + hw_l) * 8] = o0;
    *(v8h*)&d_t[(obase + 784 + hw_l) * 8] = o1;
  }
}

// ---------------- K3a: SE fc1 — one wave per (n, o); sums 2 pool partials -----
// Split form is the keeper: fused variants (r1: 64 blk, r8: 512 blk) were
// latency-bound at 2 waves/SIMD. 2304 blocks hide everything.
__global__ __launch_bounds__(256) void k3a_fc1(const float* __restrict__ d_sums2,
                                               const float* __restrict__ w_se1,
                                               const float* __restrict__ b_se1,
                                               float* __restrict__ g1) {
  const int tid = threadIdx.x;
  const int wv = tid >> 6, lane = tid & 63;
  const int n = blockIdx.y;
  const int o = blockIdx.x * 4 + wv;       // 144 outputs
  const float* wrow = &w_se1[o * CE];
  const float* s0 = &d_sums2[(size_t)n * CE];
  const float* s1 = &d_sums2[((size_t)NB + n) * CE];
  float p = 0.f;
#pragma unroll
  for (int s = 0; s < 9; ++s) {
    int cc = lane + s * 64;
    p = fmaf(wrow[cc], s0[cc] + s1[cc], p);
  }
#pragma unroll
  for (int m = 32; m >= 1; m >>= 1) p += __shfl_xor(p, m);
  if (lane == 0) {
    // g1 = clamp((p/784 + b)*4e-4*33.333 + 128, 0, 255) - 128
    g1[n * SEC + o] = clampf(fmaf(p, 1.0f / 58800.0f,
                                  fmaf(b_se1[o], 1.0f / 75.0f, 128.0f)),
                             0.0f, 255.0f) - 128.0f;
  }
}

// ---------------- K3b: SE fc2 + hardsigmoid -> f16 gate table -----------------
__global__ __launch_bounds__(256) void k3b_fc2(const float* __restrict__ g1,
                                               const float* __restrict__ w_se2,
                                               const float* __restrict__ b_se2,
                                               _Float16* __restrict__ g2h) {
  const int tid = threadIdx.x;
  const int wv = tid >> 6, lane = tid & 63;
  const int n = blockIdx.y;
  const int o = blockIdx.x * 4 + wv;       // 576 outputs
  const float* wrow = &w_se2[o * SEC];
  const float* grow = &g1[n * SEC];
  float p = fmaf(wrow[lane], grow[lane], wrow[lane + 64] * grow[lane + 64]);
  if (lane < 16) p = fmaf(wrow[lane + 128], grow[lane + 128], p);
#pragma unroll
  for (int m = 32; m >= 1; m >>= 1) p += __shfl_xor(p, m);
  if (lane == 0) {
    float t = fmaf(p, 3.0e-4f, fmaf(b_se2[o], 3.0e-4f, 3.0f));
    g2h[n * CE + o] = (_Float16)(clampf(t, 0.0f, 6.0f) * (1.0f / 6.0f)); // hardsigmoid
  }
}

// ---------------- K4: gated project 1x1 + residual add -> out fp32 -----------
// acc[7] form + XCD swizzle + DEPTH-3 load rotation (A/B/C issued 3 K-steps
// ahead). Measured: per-step time ~966 cy vs ~35 cy of MFMA -> latency-bound
// at 2.6 waves/SIMD with 1-step lookahead. 3 buffers keep ~27 loads in
// flight (~2 full steps of latency cover). VGPR ~150 -> still 3 waves/SIMD.
// Accumulation order ks=0..17 unchanged -> bit-identical results.
__global__ __launch_bounds__(192) void k4_proj(const _Float16* __restrict__ d_t,
                                               const _Float16* __restrict__ g2h,
                                               const _Float16* __restrict__ w_proj_h,
                                               const float* __restrict__ b_proj,
                                               const float* __restrict__ x,
                                               float* __restrict__ out) {
  const int tid = threadIdx.x;

  // XCD-aware remap: 896 blocks = 8 XCD x 112 slots; 14 blocks (7hw x 2co)/n
  const int flat = blockIdx.x + 7 * blockIdx.y + 14 * blockIdx.z;
  const int xcd = flat & 7, slot = flat >> 3;
  const int nl = slot / 14, w14 = slot - nl * 14;
  const int n = xcd * 8 + nl;
  const int byy = w14 / 7;
  const int co0 = byy * 48;
  const int hw0 = (w14 - byy * 7) * 112;

  const int wv = tid >> 6, lane = tid & 63;
  const int l15 = lane & 15, q = lane >> 4;

  v4f acc[7];
#pragma unroll
  for (int t = 0; t < 7; ++t) acc[t] = (v4f){0.f, 0.f, 0.f, 0.f};

  const _Float16* dbase = d_t + (((size_t)n * 72 + q) * 784 + hw0 + l15) * 8;
  const _Float16* abase = &w_proj_h[(co0 + wv * 16 + l15) * CE + q * 8];
  const _Float16* gbase = &g2h[(size_t)n * CE + q * 8];

#define K4_LOAD(SUF, KS)                                                      \
  {                                                                           \
    const int ks_ = (KS);                                                     \
    a##SUF = *(const v8h*)(abase + ks_ * 32);                                 \
    g##SUF = *(const v8h*)(gbase + ks_ * 32);                                 \
    const _Float16* dk_ = dbase + (size_t)ks_ * (4 * 784 * 8);                \
    _Pragma("unroll")                                                         \
    for (int t = 0; t < 7; ++t) b##SUF[t] = *(const v8h*)(dk_ + t * (16 * 8));\
  }
#define K4_COMPUTE(SUF)                                                       \
  {                                                                           \
    v8h ag_ = a##SUF * g##SUF;                                                \
    _Pragma("unroll")                                                         \
    for (int t = 0; t < 7; ++t)                                               \
      acc[t] = __builtin_amdgcn_mfma_f32_16x16x32_f16(ag_, b##SUF[t],         \
                                                      acc[t], 0, 0, 0);       \
  }

  v8h aA, gA, bA[7], aB, gB, bB[7], aC, gC, bC[7];
  K4_LOAD(A, 0);
  K4_LOAD(B, 1);
  K4_LOAD(C, 2);
#pragma unroll
  for (int ks = 0; ks < 18; ks += 3) {
    K4_COMPUTE(A);
    if (ks + 3 < 18) K4_LOAD(A, ks + 3);
    K4_COMPUTE(B);
    if (ks + 4 < 18) K4_LOAD(B, ks + 4);
    K4_COMPUTE(C);
    if (ks + 5 < 18) K4_LOAD(C, ks + 5);
  }

  float biaf[4];   // bias pre-folded: p = med3(fma(acc, 8e-3, biaf), 0, 255)
#pragma unroll
  for (int r = 0; r < 4; ++r)
    biaf[r] = fmaf(b_proj[co0 + wv * 16 + q * 4 + r], 8.0e-3f, 128.0f);

#pragma unroll
  for (int t = 0; t < 7; ++t) {
#pragma unroll
    for (int r = 0; r < 4; ++r) {
      int co = co0 + wv * 16 + q * 4 + r;
      int hw = hw0 + t * 16 + l15;
      float p  = clampf(fmaf(acc[t][r], 8.0e-3f, biaf[r]), 0.0f, 255.0f);
      float xv = x[(n * CO + co) * HW + hw];
      // (xv-128)*g + (p-128)*g + 128 = g*(xv+p) - 85.333..., g = 5/6
      float o = fmaf(xv + p, 0.8333333333f, -85.33333333f);
      out[(n * CO + co) * HW + hw] = clampf(o, 0.0f, 255.0f);
    }
  }
}

extern "C" void kernel_launch(void* const* d_in, const int* in_sizes, int n_in,
                              void* d_out, int out_size, void* d_ws, size_t ws_size,
                              hipStream_t stream) {
  const float* x      = (const float*)d_in[0];
  const float* w_exp  = (const float*)d_in[1];
  const float* b_exp  = (const float*)d_in[2];
  const float* w_dw   = (const float*)d_in[3];
  const float* b_dw   = (const float*)d_in[4];
  const float* w_se1  = (const float*)d_in[5];
  const float* b_se1  = (const float*)d_in[6];
  const float* w_se2  = (const float*)d_in[7];
  const float* b_se2  = (const float*)d_in[8];
  const float* w_proj = (const float*)d_in[9];
  const float* b_proj = (const float*)d_in[10];
  float* out = (float*)d_out;

  char* ws = (char*)d_ws;
  const size_t SZ_W  = (size_t)CE * CI * 2;            // 110592 B
  const size_t SZ_XF = (size_t)NB * 49 * 3 * 512 * 2;  // 9633792 B
  const size_t SZ_D  = (size_t)NB * CE * HW * 2;       // 57802752 B
  const size_t SZ_S2 = (size_t)2 * NB * CE * 4;        // 294912 B
  const size_t SZ_S  = (size_t)NB * CE * 4;            // 147456 B
  _Float16* w_exp_h  = (_Float16*)(ws);
  _Float16* w_proj_h = (_Float16*)(ws + SZ_W);
  _Float16* x_f      = (_Float16*)(ws + 2 * SZ_W);
  _Float16* d_t      = (_Float16*)(ws + 2 * SZ_W + SZ_XF);    // [n][72][784][8]
  float*    d_sums2  = (float*)   (ws + 2 * SZ_W + SZ_XF + SZ_D);
  float*    g1       = (float*)   (ws + 2 * SZ_W + SZ_XF + SZ_D + SZ_S2);
  _Float16* g2h      = (_Float16*)(ws + 2 * SZ_W + SZ_XF + SZ_D + SZ_S2 + SZ_S);
  // total ws use: ~68 MB

  k0_pack_cvt<<<dim3(49, NB + 1), 256, 0, stream>>>(x, x_f, w_exp, w_proj, w_exp_h, w_proj_h);
  k12_fused<<<dim3(36, 2, NB), 512, 0, stream>>>(x_f, w_exp_h, b_exp, w_dw, b_dw, d_t, d_sums2);
  k3a_fc1<<<dim3(36, NB), 256, 0, stream>>>(d_sums2, w_se1, b_se1, g1);
  k3b_fc2<<<dim3(144, NB), 256, 0, stream>>>(g1, w_se2, b_se2, g2h);
  k4_proj<<<dim3(7, 2, NB), 192, 0, stream>>>(d_t, g2h, w_proj_h, b_proj, x, out);
}

// Round 10
// 169.385 us; speedup vs baseline: 1.0821x; 1.0072x over previous
//
#include <hip/hip_runtime.h>

typedef _Float16 v8h __attribute__((ext_vector_type(8)));
typedef _Float16 v4h __attribute__((ext_vector_type(4)));
typedef _Float16 v2h __attribute__((ext_vector_type(2)));
typedef float v4f __attribute__((ext_vector_type(4)));

#define NB 64
#define CI 96
#define CE 576
#define CO 96
#define HW 784
#define SEC 144

#if defined(__has_builtin)
#if __has_builtin(__builtin_amdgcn_fdot2)
#define HAVE_FDOT2 1
#endif
#endif

__device__ __forceinline__ float fdot2(v2h a, v2h b, float c) {
#ifdef HAVE_FDOT2
  return __builtin_amdgcn_fdot2(a, b, c, false);
#else
  return (float)a[0] * (float)b[0] + ((float)a[1] * (float)b[1] + c);
#endif
}

__device__ __forceinline__ float clampf(float x, float lo, float hi) {
#if defined(__has_builtin)
#if __has_builtin(__builtin_amdgcn_fmed3f)
  return __builtin_amdgcn_fmed3f(x, lo, hi);   // v_med3_f32: 1 instr
#else
  return fminf(fmaxf(x, lo), hi);
#endif
#else
  return fminf(fmaxf(x, lo), hi);
#endif
}

// ---------------- K0: pack x into MFMA-B layout + convert GEMM weights -------
// One block per 16-hw tile (49 x 64 pack blocks + 49 cvt blocks).
__global__ __launch_bounds__(256) void k0_pack_cvt(const float* __restrict__ x,
                                                   _Float16* __restrict__ x_f,
                                                   const float* __restrict__ w_exp,
                                                   const float* __restrict__ w_proj,
                                                   _Float16* __restrict__ w_exp_h,
                                                   _Float16* __restrict__ w_proj_h) {
  __shared__ _Float16 xl[16][100];    // [hw_local][ci], pad 96->100
  const int tid = threadIdx.x;

  if (blockIdx.y == NB) {             // weight convert slice (49 blocks)
    for (int i = blockIdx.x * 256 + tid; i < CE * CI; i += 49 * 256) {
      w_exp_h[i]  = (_Float16)w_exp[i];
      w_proj_h[i] = (_Float16)w_proj[i];
    }
    return;
  }

  const int n = blockIdx.y;
  const int t = blockIdx.x;           // 16-hw tile index, hw0 = 16t
  const int hw0 = t * 16;

  // stage 1: 96 ci x 16 hw as 384 float4 loads (1.5 rounds)
  for (int idx = tid; idx < 384; idx += 256) {
    int ci = idx >> 2, seg = idx & 3;
    const float4 v = *(const float4*)&x[(n * CI + ci) * HW + hw0 + seg * 4];
    int r = seg * 4;
    xl[r + 0][ci] = (_Float16)(v.x - 128.0f);
    xl[r + 1][ci] = (_Float16)(v.y - 128.0f);
    xl[r + 2][ci] = (_Float16)(v.z - 128.0f);
    xl[r + 3][ci] = (_Float16)(v.w - 128.0f);
  }
  __syncthreads();

  // stage 2: 3 s-groups x 64 lanes -> v8h fragment stores (single round)
  if (tid < 192) {
    int s = tid >> 6, ln = tid & 63;
    int r = ln & 15, ci = s * 32 + (ln >> 4) * 8;
    v8h o;
#pragma unroll
    for (int j = 0; j < 8; ++j) o[j] = xl[r][ci + j];
    *(v8h*)&x_f[(((size_t)n * 49 + t) * 3 + s) * 512 + ln * 8] = o;
  }
}

// ---------------- K12: FUSED expand 1x1 (MFMA) + depthwise 5x5 ---------------
// block = (c-group of 16, image-half of 14 rows, n), 512 thr (8 waves).
// LDS ~35.8 KB -> 4 blocks/CU. Halo rows (+-2) recomputed by the expand MFMA.
// No XCD swizzle (round-4: swizzle cut FETCH 86% but cost +2 us).
// Measured-null levers (do not retry): requant VALU diet (r1), e_lds/d_tile
// pad variants (r2/r3 -- SQ_LDS_BANK_CONFLICT bit-identical at 3.76M).
__global__ __launch_bounds__(512, 8) void k12_fused(const _Float16* __restrict__ x_f,
                                                    const _Float16* __restrict__ w_exp_h,
                                                    const float* __restrict__ b_exp,
                                                    const float* __restrict__ w_dw,
                                                    const float* __restrict__ b_dw,
                                                    _Float16* __restrict__ d_t,
                                                    float* __restrict__ d_sums2) {
  __shared__ _Float16 e_lds[16][18][38];   // 21888 B; width 38: all v2h in-row
  __shared__ _Float16 d_tile[16][392];     // 12544 B
  __shared__ _Float16 w_pairs[16][5][8];   // 1280 B
  const int tid = threadIdx.x;
  const int n = blockIdx.z;
  const int h = blockIdx.y;                // image half: rows 14h..14h+13
  const int c0 = blockIdx.x * 16;

  // zero conv image (covers halo + unwritten tail halves)
  {
    unsigned long long* z = (unsigned long long*)&e_lds[0][0][0];
    for (int idx = tid; idx < 16 * 18 * 38 * 2 / 8; idx += 512) z[idx] = 0ull;
  }
  // dw weight pairs [c][dy][w0,w1,w2,w3, w1,w2,w3,w4]
  for (int idx = tid; idx < 640; idx += 512) {
    int c = idx / 40, r = idx % 40, dy = r / 8, k = r % 8;
    int tap = (k < 4) ? k : (k - 3);
    w_pairs[c][dy][k] = (_Float16)w_dw[(c0 + c) * 25 + dy * 5 + tap];
  }
  __syncthreads();

  const int wv = tid >> 6, lane = tid & 63;
  const int l15 = lane & 15, q = lane >> 4;

  // ---- phase 1: expand GEMM over 16 input rows (t-tiles 21h .. 21h+27) ----
  {
    const _Float16* wrow = &w_exp_h[(c0 + l15) * CI + q * 8];
    v8h a0 = *(const v8h*)(wrow);
    v8h a1 = *(const v8h*)(wrow + 32);
    v8h a2 = *(const v8h*)(wrow + 64);
    float bia3[4], bia2[4];                // bias pre-folded into fma constants
#pragma unroll
    for (int r = 0; r < 4; ++r) {
      float b = b_exp[c0 + q * 4 + r];
      bia3[r] = fmaf(b, 5.0e-4f, 3.0f);                 // deq + 3 path
      bia2[r] = b * (5.0e-4f * 25.0f / 6.0f);           // deq*25/6 path
    }

    const int ir0 = 14 * h - 2;                 // input row at LDS row 0
    const _Float16* xb = x_f + (size_t)n * (49 * 3 * 512) + lane * 8;
    // incremental y/xx tracking: per-iter hw += 128 = 4*28 + 16
    int hw0 = (21 * h + wv) * 16 + l15;
    int y = hw0 / 28;
    int xx = hw0 - y * 28;
#pragma unroll
    for (int it = 0; it < 4; ++it) {
      int t_l = wv + it * 8;
      if (t_l < 28) {                           // wave-uniform guard
        int t = 21 * h + t_l;
        const _Float16* xt = xb + (size_t)t * (3 * 512);
        v8h b0 = *(const v8h*)(xt);
        v8h b1 = *(const v8h*)(xt + 512);
        v8h b2 = *(const v8h*)(xt + 1024);
        v4f acc = (v4f){0.f, 0.f, 0.f, 0.f};
        acc = __builtin_amdgcn_mfma_f32_16x16x32_f16(a0, b0, acc, 0, 0, 0);
        acc = __builtin_amdgcn_mfma_f32_16x16x32_f16(a1, b1, acc, 0, 0, 0);
        acc = __builtin_amdgcn_mfma_f32_16x16x32_f16(a2, b2, acc, 0, 0, 0);
        _Float16* dst = &e_lds[q * 4][y - ir0][6 + xx];
#pragma unroll
        for (int r = 0; r < 4; ++r) {
          // hardswish+requant: fma, med3, fma, mul, med3, cvt
          float t1  = fmaf(acc[r], 5.0e-4f, bia3[r]);               // deq+3
          float cl  = clampf(t1, 0.0f, 6.0f);
          float a2v = fmaf(acc[r], 5.0e-4f * 25.0f / 6.0f, bia2[r]); // deq*25/6
          float ev  = clampf(a2v * cl, -128.0f, 127.0f);            // e-128
          dst[r * (18 * 38)] = (_Float16)ev;                        // imm-offset stores
        }
      }
      xx += 16; y += 4;
      if (xx >= 28) { xx -= 28; ++y; }
    }
  }
  __syncthreads();

  // ---- phase 2: depthwise 5x5; lane = (row ry = l>>1, x-half xh = l&1) ----
  const int c = tid >> 5, l = tid & 31;
  v2h W01[5], W23[5], W12[5], W34[5];
  float W0s[5], W4s[5];
#pragma unroll
  for (int dy = 0; dy < 5; ++dy) {
    W01[dy] = *(const v2h*)&w_pairs[c][dy][0];
    W23[dy] = *(const v2h*)&w_pairs[c][dy][2];
    W12[dy] = *(const v2h*)&w_pairs[c][dy][4];
    W34[dy] = *(const v2h*)&w_pairs[c][dy][6];
    W0s[dy] = (float)W01[dy][0];
    W4s[dy] = (float)W34[dy][1];
  }
  const float bc = b_dw[c0 + c];

#define DW_REQUANT(oo, dvv)                                                   \
  {                                                                           \
    float t1_ = fmaf((oo), 4.0e-4f, 3.0f);                                    \
    float cl_ = clampf(t1_, 0.0f, 6.0f);                                      \
    dvv = clampf((oo) * (4.0e-4f * 25.0f / 6.0f) * cl_, -128.0f, 127.0f);     \
  }

  float csum = 0.0f;
  if (l < 28) {
    const int ry = l >> 1;       // local output row 0..13
    const int bx = (l & 1) * 14; // x-half base
    v2h P0[5], P1[5], P2[5], P3[5];
#pragma unroll
    for (int dy = 0; dy < 5; ++dy) {
      const _Float16* row = &e_lds[c][ry + dy][bx];
      P0[dy] = *(const v2h*)(row + 4);    // pixels bx-2,bx-1
      P1[dy] = *(const v2h*)(row + 6);
      P2[dy] = *(const v2h*)(row + 8);
      P3[dy] = *(const v2h*)(row + 10);
    }
#pragma unroll
    for (int xi = 0; xi < 3; ++xi) {      // x0 = bx, bx+4, bx+8
      const int x0 = bx + xi * 4;
      float o0 = bc, o1 = bc, o2 = bc, o3 = bc;
#pragma unroll
      for (int dy = 0; dy < 5; ++dy) {
        o0 = fdot2(P0[dy], W01[dy], o0);
        o0 = fdot2(P1[dy], W23[dy], o0);
        o0 += (float)P2[dy][0] * W4s[dy];
        o1 += (float)P0[dy][1] * W0s[dy];
        o1 = fdot2(P1[dy], W12[dy], o1);
        o1 = fdot2(P2[dy], W34[dy], o1);
        o2 = fdot2(P1[dy], W01[dy], o2);
        o2 = fdot2(P2[dy], W23[dy], o2);
        o2 += (float)P3[dy][0] * W4s[dy];
        o3 += (float)P1[dy][1] * W0s[dy];
        o3 = fdot2(P2[dy], W12[dy], o3);
        o3 = fdot2(P3[dy], W34[dy], o3);
      }
      float d0, d1, d2, d3;
      DW_REQUANT(o0, d0); DW_REQUANT(o1, d1);
      DW_REQUANT(o2, d2); DW_REQUANT(o3, d3);
      csum += (d0 + d1) + (d2 + d3);
      v2h dva, dvb;
      dva[0] = (_Float16)d0; dva[1] = (_Float16)d1;
      dvb[0] = (_Float16)d2; dvb[1] = (_Float16)d3;
      *(v2h*)&d_tile[c][ry * 28 + x0]     = dva;   // b32 stores, 4B-aligned
      *(v2h*)&d_tile[c][ry * 28 + x0 + 2] = dvb;
      // slide window (last slide reads halves up to 37 -> zeroed tail, in-row)
#pragma unroll
      for (int dy = 0; dy < 5; ++dy) {
        const _Float16* row = &e_lds[c][ry + dy][bx];
        P0[dy] = P2[dy];
        P1[dy] = P3[dy];
        P2[dy] = *(const v2h*)(row + x0 - bx + 12);
        P3[dy] = *(const v2h*)(row + x0 - bx + 14);
      }
    }
    {  // tail: x0 = bx+12, outputs o0,o1 only
      float o0 = bc, o1 = bc;
#pragma unroll
      for (int dy = 0; dy < 5; ++dy) {
        o0 = fdot2(P0[dy], W01[dy], o0);
        o0 = fdot2(P1[dy], W23[dy], o0);
        o0 += (float)P2[dy][0] * W4s[dy];
        o1 += (float)P0[dy][1] * W0s[dy];
        o1 = fdot2(P1[dy], W12[dy], o1);
        o1 = fdot2(P2[dy], W34[dy], o1);
      }
      float d0, d1;
      DW_REQUANT(o0, d0); DW_REQUANT(o1, d1);
      csum += d0 + d1;
      v2h dv; dv[0] = (_Float16)d0; dv[1] = (_Float16)d1;
      *(v2h*)&d_tile[c][ry * 28 + bx + 12] = dv;
    }
  }
#pragma unroll
  for (int m = 16; m >= 1; m >>= 1) csum += __shfl_xor(csum, m);
  if (l == 0) d_sums2[((size_t)h * NB + n) * CE + c0 + c] = csum;

  __syncthreads();
  // ---- phase 3: k-packed writeout d_t[n][cg][hw][8], hw in [392h, 392h+392) ----
  const size_t obase = ((size_t)n * 72 + (c0 >> 3)) * 784 + 392 * h;
  if (tid < 392) {
    int hw_l = tid;
    v8h o0, o1;
#pragma unroll
    for (int j = 0; j < 8; ++j) { o0[j] = d_tile[j][hw_l]; o1[j] = d_tile[8 + j][hw_l]; }
    *(v8h*)&d_t[(obase + hw_l) * 8] = o0;
    *(v8h*)&d_t[(obase + 784 + hw_l) * 8] = o1;
  }
}

// ---------------- K3a: SE fc1 — one wave per (n, o); sums 2 pool partials -----
// Split form is the keeper: fused variants (r1: 64 blk, r3: fence-tail,
// r8: 512 blk redundant) all regressed. 2304 blocks hide everything.
__global__ __launch_bounds__(256) void k3a_fc1(const float* __restrict__ d_sums2,
                                               const float* __restrict__ w_se1,
                                               const float* __restrict__ b_se1,
                                               float* __restrict__ g1) {
  const int tid = threadIdx.x;
  const int wv = tid >> 6, lane = tid & 63;
  const int n = blockIdx.y;
  const int o = blockIdx.x * 4 + wv;       // 144 outputs
  const float* wrow = &w_se1[o * CE];
  const float* s0 = &d_sums2[(size_t)n * CE];
  const float* s1 = &d_sums2[((size_t)NB + n) * CE];
  float p = 0.f;
#pragma unroll
  for (int s = 0; s < 9; ++s) {
    int cc = lane + s * 64;
    p = fmaf(wrow[cc], s0[cc] + s1[cc], p);
  }
#pragma unroll
  for (int m = 32; m >= 1; m >>= 1) p += __shfl_xor(p, m);
  if (lane == 0) {
    // g1 = clamp((p/784 + b)*4e-4*33.333 + 128, 0, 255) - 128
    g1[n * SEC + o] = clampf(fmaf(p, 1.0f / 58800.0f,
                                  fmaf(b_se1[o], 1.0f / 75.0f, 128.0f)),
                             0.0f, 255.0f) - 128.0f;
  }
}

// ---------------- K3b: SE fc2 + hardsigmoid -> f16 gate table -----------------
__global__ __launch_bounds__(256) void k3b_fc2(const float* __restrict__ g1,
                                               const float* __restrict__ w_se2,
                                               const float* __restrict__ b_se2,
                                               _Float16* __restrict__ g2h) {
  const int tid = threadIdx.x;
  const int wv = tid >> 6, lane = tid & 63;
  const int n = blockIdx.y;
  const int o = blockIdx.x * 4 + wv;       // 576 outputs
  const float* wrow = &w_se2[o * SEC];
  const float* grow = &g1[n * SEC];
  float p = fmaf(wrow[lane], grow[lane], wrow[lane + 64] * grow[lane + 64]);
  if (lane < 16) p = fmaf(wrow[lane + 128], grow[lane + 128], p);
#pragma unroll
  for (int m = 32; m >= 1; m >>= 1) p += __shfl_xor(p, m);
  if (lane == 0) {
    float t = fmaf(p, 3.0e-4f, fmaf(b_se2[o], 3.0e-4f, 3.0f));
    g2h[n * CE + o] = (_Float16)(clampf(t, 0.0f, 6.0f) * (1.0f / 6.0f)); // hardsigmoid
  }
}

// ---------------- K4: gated project 1x1 + residual add -> out fp32 -----------
// acc[7] + depth-2 ping-pong + XCD swizzle: the measured optimum.
// Falsified alternatives: acc[1]@67% occupancy (r6: +33 us — reuse beats
// occupancy), depth-3 rotation (r9: null — latency already covered at
// depth 2; kernel is L2/HBM-path-bound, ~3.3 TB/s effective).
__global__ __launch_bounds__(192) void k4_proj(const _Float16* __restrict__ d_t,
                                               const _Float16* __restrict__ g2h,
                                               const _Float16* __restrict__ w_proj_h,
                                               const float* __restrict__ b_proj,
                                               const float* __restrict__ x,
                                               float* __restrict__ out) {
  const int tid = threadIdx.x;

  // XCD-aware remap: 896 blocks = 8 XCD x 112 slots; 14 blocks (7hw x 2co)/n
  const int flat = blockIdx.x + 7 * blockIdx.y + 14 * blockIdx.z;
  const int xcd = flat & 7, slot = flat >> 3;
  const int nl = slot / 14, w14 = slot - nl * 14;
  const int n = xcd * 8 + nl;
  const int byy = w14 / 7;
  const int co0 = byy * 48;
  const int hw0 = (w14 - byy * 7) * 112;

  const int wv = tid >> 6, lane = tid & 63;
  const int l15 = lane & 15, q = lane >> 4;

  v4f acc[7];
#pragma unroll
  for (int t = 0; t < 7; ++t) acc[t] = (v4f){0.f, 0.f, 0.f, 0.f};

  const _Float16* dbase = d_t + (((size_t)n * 72 + q) * 784 + hw0 + l15) * 8;
  const _Float16* abase = &w_proj_h[(co0 + wv * 16 + l15) * CE + q * 8];
  const _Float16* gbase = &g2h[(size_t)n * CE + q * 8];

#define K4_LOAD(SUF, KS)                                                      \
  {                                                                           \
    const int ks_ = (KS);                                                     \
    a##SUF = *(const v8h*)(abase + ks_ * 32);                                 \
    g##SUF = *(const v8h*)(gbase + ks_ * 32);                                 \
    const _Float16* dk_ = dbase + (size_t)ks_ * (4 * 784 * 8);                \
    _Pragma("unroll")                                                         \
    for (int t = 0; t < 7; ++t) b##SUF[t] = *(const v8h*)(dk_ + t * (16 * 8));\
  }
#define K4_COMPUTE(SUF)                                                       \
  {                                                                           \
    v8h ag_ = a##SUF * g##SUF;                                                \
    _Pragma("unroll")                                                         \
    for (int t = 0; t < 7; ++t)                                               \
      acc[t] = __builtin_amdgcn_mfma_f32_16x16x32_f16(ag_, b##SUF[t],         \
                                                      acc[t], 0, 0, 0);       \
  }

  v8h aA, gA, bA[7], aB, gB, bB[7];
  K4_LOAD(A, 0);
#pragma unroll
  for (int ks = 0; ks < 18; ks += 2) {
    K4_LOAD(B, ks + 1);          // prefetch odd while computing even
    K4_COMPUTE(A);
    if (ks + 2 < 18) K4_LOAD(A, ks + 2);  // prefetch next even
    K4_COMPUTE(B);
  }

  float biaf[4];   // bias pre-folded: p = med3(fma(acc, 8e-3, biaf), 0, 255)
#pragma unroll
  for (int r = 0; r < 4; ++r)
    biaf[r] = fmaf(b_proj[co0 + wv * 16 + q * 4 + r], 8.0e-3f, 128.0f);

#pragma unroll
  for (int t = 0; t < 7; ++t) {
#pragma unroll
    for (int r = 0; r < 4; ++r) {
      int co = co0 + wv * 16 + q * 4 + r;
      int hw = hw0 + t * 16 + l15;
      float p  = clampf(fmaf(acc[t][r], 8.0e-3f, biaf[r]), 0.0f, 255.0f);
      float xv = x[(n * CO + co) * HW + hw];
      // (xv-128)*g + (p-128)*g + 128 = g*(xv+p) - 85.333..., g = 5/6
      float o = fmaf(xv + p, 0.8333333333f, -85.33333333f);
      out[(n * CO + co) * HW + hw] = clampf(o, 0.0f, 255.0f);
    }
  }
}

extern "C" void kernel_launch(void* const* d_in, const int* in_sizes, int n_in,
                              void* d_out, int out_size, void* d_ws, size_t ws_size,
                              hipStream_t stream) {
  const float* x      = (const float*)d_in[0];
  const float* w_exp  = (const float*)d_in[1];
  const float* b_exp  = (const float*)d_in[2];
  const float* w_dw   = (const float*)d_in[3];
  const float* b_dw   = (const float*)d_in[4];
  const float* w_se1  = (const float*)d_in[5];
  const float* b_se1  = (const float*)d_in[6];
  const float* w_se2  = (const float*)d_in[7];
  const float* b_se2  = (const float*)d_in[8];
  const float* w_proj = (const float*)d_in[9];
  const float* b_proj = (const float*)d_in[10];
  float* out = (float*)d_out;

  char* ws = (char*)d_ws;
  const size_t SZ_W  = (size_t)CE * CI * 2;            // 110592 B
  const size_t SZ_XF = (size_t)NB * 49 * 3 * 512 * 2;  // 9633792 B
  const size_t SZ_D  = (size_t)NB * CE * HW * 2;       // 57802752 B
  const size_t SZ_S2 = (size_t)2 * NB * CE * 4;        // 294912 B
  const size_t SZ_S  = (size_t)NB * CE * 4;            // 147456 B
  _Float16* w_exp_h  = (_Float16*)(ws);
  _Float16* w_proj_h = (_Float16*)(ws + SZ_W);
  _Float16* x_f      = (_Float16*)(ws + 2 * SZ_W);
  _Float16* d_t      = (_Float16*)(ws + 2 * SZ_W + SZ_XF);    // [n][72][784][8]
  float*    d_sums2  = (float*)   (ws + 2 * SZ_W + SZ_XF + SZ_D);
  float*    g1       = (float*)   (ws + 2 * SZ_W + SZ_XF + SZ_D + SZ_S2);
  _Float16* g2h      = (_Float16*)(ws + 2 * SZ_W + SZ_XF + SZ_D + SZ_S2 + SZ_S);
  // total ws use: ~68 MB

  k0_pack_cvt<<<dim3(49, NB + 1), 256, 0, stream>>>(x, x_f, w_exp, w_proj, w_exp_h, w_proj_h);
  k12_fused<<<dim3(36, 2, NB), 512, 0, stream>>>(x_f, w_exp_h, b_exp, w_dw, b_dw, d_t, d_sums2);
  k3a_fc1<<<dim3(36, NB), 256, 0, stream>>>(d_sums2, w_se1, b_se1, g1);
  k3b_fc2<<<dim3(144, NB), 256, 0, stream>>>(g1, w_se2, b_se2, g2h);
  k4_proj<<<dim3(7, 2, NB), 192, 0, stream>>>(d_t, g2h, w_proj_h, b_proj, x, out);
}